// Round 11
// baseline (329.669 us; speedup 1.0000x reference)
//
#include <hip/hip_runtime.h>
#include <hip/hip_bf16.h>
#include <stdint.h>

#define NTOK 65536
#define DIM 512
#define NEXP 4
#define REG 14336  // per-pair-group slot region (expected ~10923; 112 blocks of 128)

using u16 = unsigned short;
using u32 = unsigned int;
typedef __attribute__((ext_vector_type(4))) float f32x4;
typedef __attribute__((ext_vector_type(8))) short bf16x8;
typedef __attribute__((ext_vector_type(8))) u16 u16x8;
typedef __attribute__((ext_vector_type(4))) u16 u16x4;

__device__ __forceinline__ u16 f2bf(float f) {
  u32 u = __builtin_bit_cast(u32, f);
  u32 r = (u + 0x7FFFu + ((u >> 16) & 1u)) >> 16;
  return (u16)r;
}
__device__ __forceinline__ float bf2f(u16 v) {
  return __builtin_bit_cast(float, (u32)v << 16);
}

#define GLOAD_LDS16(gp, lp)                                                    \
  __builtin_amdgcn_global_load_lds(                                            \
      (const __attribute__((address_space(1))) void*)(gp),                     \
      (__attribute__((address_space(3))) void*)(lp), 16, 0, 0)

#define FENCE asm volatile("" ::: "memory")
#define BARRIER { FENCE; __builtin_amdgcn_s_barrier(); FENCE; }
#define LGKM0 { asm volatile("s_waitcnt lgkmcnt(0)" ::: "memory"); __builtin_amdgcn_sched_barrier(0); }
#define VMCNT_(n) asm volatile("s_waitcnt vmcnt(" #n ")" ::: "memory")
#define VMCNT(n) VMCNT_(n)

// 128B-row LDS (outnorm): logical (row, 16B-chunk 0..7) -> phys chunk = c ^ (row&7)
__device__ __forceinline__ const bf16x8* lds_frag(const u16* base, int row, int chunk) {
  return (const bf16x8*)((const char*)base + row * 128 + (((chunk) ^ (row & 7)) << 4));
}
// 64B-row LDS (expert, BK=32): logical chunk c (0..3) at phys (c + rot(row))&3,
// rot = ((row&15)>>1)&3. rchByte = precomputed phys byte offset for this lane.
__device__ __forceinline__ const bf16x8* frag32(const u16* base, int row, int rchByte) {
  return (const bf16x8*)((const char*)base + row * 64 + rchByte);
}

// ---------------- K0a: expert_w transpose + fp32->bf16 + cnt zero ----------------
__global__ void wconv(const float* __restrict__ ew, u16* __restrict__ ewt,
                      int* __restrict__ cnt) {
  __shared__ float tile[32][33];
  int mat = blockIdx.y;
  if (blockIdx.x == 0 && mat == 0 && threadIdx.x < 6) cnt[threadIdx.x] = 0;
  const float* s = ew + (size_t)mat * DIM * DIM;
  u16* d = ewt + (size_t)mat * DIM * DIM;
  int tx = blockIdx.x & 15, ty = blockIdx.x >> 4;
  int lx = threadIdx.x & 31, ly0 = threadIdx.x >> 5;
#pragma unroll
  for (int i = 0; i < 4; ++i) {
    int ly = ly0 + i * 8;
    tile[ly][lx] = s[(size_t)(ty * 32 + ly) * DIM + tx * 32 + lx];
  }
  __syncthreads();
#pragma unroll
  for (int i = 0; i < 4; ++i) {
    int ly = ly0 + i * 8;
    d[(size_t)(tx * 32 + ly) * DIM + ty * 32 + lx] = f2bf(tile[lx][ly]);
  }
}

// ---------------- K0b: pack out_w into MFMA-fragment order ----------------
__global__ void owpack(const float* __restrict__ ow, u16* __restrict__ owt3) {
  int lane = threadIdx.x & 63, wv = threadIdx.x >> 6;
  int frag = blockIdx.x * 4 + wv;  // 0..511
  int j = frag & 7, kc = (frag >> 3) & 1, t = (frag >> 4) & 7, strip = frag >> 7;
  int r16 = lane & 15, lg = lane >> 4;
  int h = strip * 128 + j * 16 + r16;
  int d0 = t * 64 + kc * 32 + lg * 8;
  u16x8 o;
#pragma unroll
  for (int q = 0; q < 8; ++q) o[q] = f2bf(ow[(size_t)(d0 + q) * DIM + h]);
  *(u16x8*)(owt3 + (size_t)frag * 512 + lane * 8) = o;
}

// ---------------- K1: router (fp32) + x -> bf16 ----------------
__global__ void router_kernel(const float* __restrict__ x, const float* __restrict__ rw,
                              const float* __restrict__ rb, u16* __restrict__ xb,
                              int* __restrict__ pp, float2* __restrict__ wab) {
  int lane = threadIdx.x & 63, wave = threadIdx.x >> 6;
  size_t t = (size_t)blockIdx.x * 4 + wave;
  const float* xr = x + t * DIM + lane * 8;
  f32x4 v0 = *(const f32x4*)xr;
  f32x4 v1 = *(const f32x4*)(xr + 4);
  float l0 = 0.f, l1 = 0.f, l2 = 0.f, l3 = 0.f;
  const float* rwp = rw + (size_t)lane * 32;
#pragma unroll
  for (int j = 0; j < 8; ++j) {
    float xv = (j < 4) ? v0[j] : v1[j - 4];
    f32x4 r = *(const f32x4*)(rwp + j * 4);
    l0 += xv * r[0]; l1 += xv * r[1]; l2 += xv * r[2]; l3 += xv * r[3];
  }
#pragma unroll
  for (int off = 32; off; off >>= 1) {
    l0 += __shfl_xor(l0, off); l1 += __shfl_xor(l1, off);
    l2 += __shfl_xor(l2, off); l3 += __shfl_xor(l3, off);
  }
  float lv[4] = {l0 + rb[0], l1 + rb[1], l2 + rb[2], l3 + rb[3]};
  int i0 = 0; float b0 = lv[0];
#pragma unroll
  for (int e = 1; e < 4; ++e) if (lv[e] > b0) { b0 = lv[e]; i0 = e; }
  int i1 = (i0 == 0) ? 1 : 0; float b1 = lv[i1];
#pragma unroll
  for (int e = 0; e < 4; ++e) if (e != i0 && lv[e] > b1) { b1 = lv[e]; i1 = e; }
  float ex = __expf(b1 - b0);
  float w0 = 1.0f / (1.0f + ex);
  float w1 = ex * w0;
  if (lane == 0) {
    int a = (i0 < i1) ? i0 : i1;
    int b = (i0 < i1) ? i1 : i0;
    const int ptab[16] = {-1, 0, 1, 2, -1, -1, 3, 4, -1, -1, -1, 5, -1, -1, -1, -1};
    pp[t] = ptab[a * 4 + b];
    float wa = (a == i0) ? w0 : w1;
    float wb = (a == i0) ? w1 : w0;
    wab[t] = make_float2(wa, wb);
  }
  u16x8 o;
#pragma unroll
  for (int j = 0; j < 4; ++j) { o[j] = f2bf(v0[j]); o[4 + j] = f2bf(v1[j]); }
  *(u16x8*)(xb + t * DIM + lane * 8) = o;
}

// ---------------- K2: wave-aggregated group assignment + scatter ----------------
__global__ void assignscatter(const int* __restrict__ pp, const float2* __restrict__ wab,
                              int* __restrict__ cnt, int* __restrict__ list,
                              float2* __restrict__ wpair) {
  int t = blockIdx.x * 256 + threadIdx.x;
  int lane = threadIdx.x & 63;
  int p = pp[t];
  float2 w = wab[t];
  int pos = 0;
#pragma unroll
  for (int q = 0; q < 6; ++q) {
    unsigned long long m = __ballot(p == q);
    if (p == q) {
      int rank = __popcll(m & ((1ull << lane) - 1ull));
      int leader = __ffsll((long long)m) - 1;
      int base = 0;
      if (lane == leader) base = atomicAdd(&cnt[q], (int)__popcll(m));
      base = __shfl(base, leader);
      pos = base + rank;
    }
  }
  int slot = p * REG + pos;
  if (pos < REG) {
    list[slot] = t;
    wpair[slot] = w;
  }
}

// ---------------- K3: sparse expert GEMM, dual-acc, ONE barrier per K-step ----
// Fully unrolled 16 steps, 3-buffer rotation. Step T: STAGE(T+2) first (its
// buffer's readers finished before end-of-(T-1) barrier), 12 swizzled ds_reads,
// 32 MFMA under setprio, counted VMCNT(6) (stage T+1 resident; T+2 in flight),
// ONE barrier. Loads span barriers (T4); never drained to 0 until the tail.
__global__ __launch_bounds__(256, 2) void expert_gemm(
    const u16* __restrict__ xb, const u16* __restrict__ ewt,
    const float* __restrict__ ebias, const int* __restrict__ cnt,
    const int* __restrict__ list, const float2* __restrict__ wpair,
    u16* __restrict__ comb) {
  __shared__ u16 Asl[3][128 * 32];
  __shared__ u16 Bal[3][128 * 32];
  __shared__ u16 Bbl[3][128 * 32];
  int tid = threadIdx.x, lane = tid & 63, wave = tid >> 6;
  int wy = wave >> 1, wx = wave & 1;
  int b = blockIdx.x;
  int chunk = b >> 5, within = b & 31;
  int panel = chunk * 8 + (within & 7);
  int nblk = within >> 3;
  int p = panel / (REG / 128);
  int m0 = panel * 128;
  int cntp = cnt[p];
  if (m0 - p * REG >= cntp) return;
  int n0 = nblk * 128;
  const int ea2[6] = {0, 0, 0, 1, 1, 2};
  const int eb2[6] = {1, 2, 3, 2, 3, 3};
  int eA = ea2[p], eB = eb2[p];

  int r4 = lane >> 2, c4 = lane & 3;
  int rot = (r4 >> 1) & 3;
  int kch = ((c4 - rot) & 3) * 8;
  int r16 = lane & 15, lg = lane >> 4;
  int rchB = (((lg + ((r16 >> 1) & 3)) & 3)) * 16;

  int sid2[2];
#pragma unroll
  for (int j = 0; j < 2; ++j) {
    int slot = m0 + wave * 32 + j * 16 + r4;
    int idv = list[slot];
    sid2[j] = ((slot - p * REG) < cntp) ? idv : 0;
  }
  // fixed per-lane global bases; K offset is a compile-time immediate per step
  const u16* a0b = xb + (size_t)sid2[0] * DIM + kch;
  const u16* a1b = xb + (size_t)sid2[1] * DIM + kch;
  const u16* bab = ewt + (size_t)eA * DIM * DIM + (size_t)(n0 + wave * 32 + r4) * DIM + kch;
  const u16* bbb = ewt + (size_t)eB * DIM * DIM + (size_t)(n0 + wave * 32 + r4) * DIM + kch;

  f32x4 accA[4][4], accB[4][4];
#pragma unroll
  for (int i = 0; i < 4; ++i)
#pragma unroll
    for (int j = 0; j < 4; ++j) { accA[i][j] = (f32x4)(0.f); accB[i][j] = (f32x4)(0.f); }

#define STAGE(BI, KS)                                                          \
  do {                                                                         \
    GLOAD_LDS16(a0b + (KS) * 32, Asl[BI] + (wave * 32) * 32);                  \
    GLOAD_LDS16(a1b + (KS) * 32, Asl[BI] + (wave * 32 + 16) * 32);             \
    GLOAD_LDS16(bab + (KS) * 32, Bal[BI] + (wave * 32) * 32);                  \
    GLOAD_LDS16(bab + 16 * DIM + (KS) * 32, Bal[BI] + (wave * 32 + 16) * 32);  \
    GLOAD_LDS16(bbb + (KS) * 32, Bbl[BI] + (wave * 32) * 32);                  \
    GLOAD_LDS16(bbb + 16 * DIM + (KS) * 32, Bbl[BI] + (wave * 32 + 16) * 32);  \
  } while (0)

  STAGE(0, 0); STAGE(1, 1);
  VMCNT(6);   // tile 0 resident; tile 1's 6 loads stay in flight
  BARRIER;

  // one fully-static K-step, ONE barrier; T is a literal 0..15
#define KST(T, WC)                                                             \
  {                                                                            \
    if ((T) + 2 < 16) STAGE(((T) + 2) % 3, (T) + 2);                           \
    bf16x8 a[4], ba[4], bb[4];                                                 \
    _Pragma("unroll") for (int i = 0; i < 4; ++i) {                            \
      a[i]  = *frag32(Asl[(T) % 3], wy * 64 + i * 16 + r16, rchB);             \
      ba[i] = *frag32(Bal[(T) % 3], wx * 64 + i * 16 + r16, rchB);             \
      bb[i] = *frag32(Bbl[(T) % 3], wx * 64 + i * 16 + r16, rchB);             \
    }                                                                          \
    __builtin_amdgcn_s_setprio(1);                                             \
    _Pragma("unroll") for (int i = 0; i < 4; ++i)                              \
      _Pragma("unroll") for (int j = 0; j < 4; ++j)                            \
        accA[i][j] = __builtin_amdgcn_mfma_f32_16x16x32_bf16(a[i], ba[j], accA[i][j], 0, 0, 0); \
    _Pragma("unroll") for (int i = 0; i < 4; ++i)                              \
      _Pragma("unroll") for (int j = 0; j < 4; ++j)                            \
        accB[i][j] = __builtin_amdgcn_mfma_f32_16x16x32_bf16(a[i], bb[j], accB[i][j], 0, 0, 0); \
    __builtin_amdgcn_s_setprio(0);                                             \
    WC;                                                                        \
  }

  KST(0,  { VMCNT(6); BARRIER; })
  KST(1,  { VMCNT(6); BARRIER; })
  KST(2,  { VMCNT(6); BARRIER; })
  KST(3,  { VMCNT(6); BARRIER; })
  KST(4,  { VMCNT(6); BARRIER; })
  KST(5,  { VMCNT(6); BARRIER; })
  KST(6,  { VMCNT(6); BARRIER; })
  KST(7,  { VMCNT(6); BARRIER; })
  KST(8,  { VMCNT(6); BARRIER; })
  KST(9,  { VMCNT(6); BARRIER; })
  KST(10, { VMCNT(6); BARRIER; })
  KST(11, { VMCNT(6); BARRIER; })
  KST(12, { VMCNT(6); BARRIER; })
  KST(13, { VMCNT(6); BARRIER; })
  KST(14, { VMCNT(0); BARRIER; })
  KST(15, {})
#undef KST
#undef STAGE

  float bA4[4], bB4[4];
#pragma unroll
  for (int j = 0; j < 4; ++j) {
    int h = n0 + wx * 64 + j * 16 + r16;
    bA4[j] = ebias[eA * DIM + h];
    bB4[j] = ebias[eB * DIM + h];
  }
#pragma unroll
  for (int i = 0; i < 4; ++i) {
    int rb = wy * 64 + i * 16 + lg * 4;
#pragma unroll
    for (int rr = 0; rr < 4; ++rr) {
      int slot = m0 + rb + rr;
      bool val = (slot - p * REG) < cntp;
      int id = list[slot];
      float2 wv = wpair[slot];
#pragma unroll
      for (int j = 0; j < 4; ++j) {
        float zA = accA[i][j][rr] + bA4[j];
        float zB = accB[i][j][rr] + bB4[j];
        float sA = zA / (1.0f + __expf(-zA));
        float sB = zB / (1.0f + __expf(-zB));
        float v = wv.x * sA + wv.y * sB;
        if (val) {
          int h = n0 + wx * 64 + j * 16 + r16;
          comb[(size_t)id * DIM + h] = f2bf(v);
        }
      }
    }
  }
}

// ---------------- K4: fused out-proj + bias + residual(bf16 xb) + RMSNorm ----------
// Swapped-operand MFMA: C rows = 4 consecutive h, cols = token.
__global__ __launch_bounds__(256, 2) void outnorm(
    const u16* __restrict__ comb, const u16* __restrict__ owt3,
    const float* __restrict__ ob, const u16* __restrict__ xb,
    const float* __restrict__ nw, float* __restrict__ out) {
  __shared__ u16 As[3][64 * 64];   // 24 KB
  __shared__ float rowsum[64][4];
  int tid = threadIdx.x, lane = tid & 63, w = tid >> 6;  // 4 waves
  int m0 = blockIdx.x * 64;
  int r16 = lane & 15, lg = lane >> 4;
  int rl = lane >> 3;
  int scb = ((lane & 7) ^ rl) * 8;
  int n0w = w * 128;

  f32x4 acc[8][4];  // [h-frag][token-frag]
#pragma unroll
  for (int j = 0; j < 8; ++j)
#pragma unroll
    for (int i = 0; i < 4; ++i) acc[j][i] = (f32x4)(0.f);

#define OSTG(bi, ks)                                                           \
  _Pragma("unroll") for (int jj = 0; jj < 2; ++jj) {                           \
    GLOAD_LDS16(comb + (size_t)(m0 + w * 16 + jj * 8 + rl) * DIM + (ks) * 64 + scb, \
                As[bi] + (w * 16 + jj * 8) * 64);                              \
  }
#define LOADB(BV, HH)                                                          \
  {                                                                            \
    const u16* bp_ = owt3 +                                                    \
        ((size_t)(((w * 8 + ((HH) >> 1)) * 2 + ((HH) & 1)) * 8)) * 512 + lane * 8; \
    _Pragma("unroll") for (int jj = 0; jj < 8; ++jj)                           \
      BV[jj] = *(const bf16x8*)(bp_ + jj * 512);                               \
  }
#define HSTEP(H, BC, BN, WC)                                                   \
  {                                                                            \
    if (((H) & 1) == 0 && ((H) >> 1) + 2 < 8) OSTG((((H) >> 1) + 2) % 3, ((H) >> 1) + 2); \
    if ((H) + 1 < 16) LOADB(BN, (H) + 1);                                      \
    bf16x8 af[4];                                                              \
    _Pragma("unroll") for (int ii = 0; ii < 4; ++ii)                           \
      af[ii] = *lds_frag(As[((H) >> 1) % 3], ii * 16 + r16, ((H) & 1) * 4 + lg); \
    LGKM0;                                                                     \
    __builtin_amdgcn_s_setprio(1);                                             \
    _Pragma("unroll") for (int jj = 0; jj < 8; ++jj)                           \
      _Pragma("unroll") for (int ii = 0; ii < 4; ++ii)                         \
        acc[jj][ii] = __builtin_amdgcn_mfma_f32_16x16x32_bf16(BC[jj], af[ii], acc[jj][ii], 0, 0, 0); \
    __builtin_amdgcn_s_setprio(0);                                             \
    WC;                                                                        \
  }

  bf16x8 BE[8], BO[8];
  OSTG(0, 0); OSTG(1, 1);
  LOADB(BE, 0);
  VMCNT(10);   // drain A0 (A1 2 + BE0 8 stay in flight)
  BARRIER;

  HSTEP(0,  BE, BO, {})
  HSTEP(1,  BO, BE, { VMCNT(10); BARRIER; })
  HSTEP(2,  BE, BO, {})
  HSTEP(3,  BO, BE, { VMCNT(10); BARRIER; })
  HSTEP(4,  BE, BO, {})
  HSTEP(5,  BO, BE, { VMCNT(10); BARRIER; })
  HSTEP(6,  BE, BO, {})
  HSTEP(7,  BO, BE, { VMCNT(10); BARRIER; })
  HSTEP(8,  BE, BO, {})
  HSTEP(9,  BO, BE, { VMCNT(10); BARRIER; })
  HSTEP(10, BE, BO, {})
  HSTEP(11, BO, BE, { VMCNT(10); BARRIER; })
  HSTEP(12, BE, BO, {})
  HSTEP(13, BO, BE, { VMCNT(8); BARRIER; })
  HSTEP(14, BE, BO, {})
  HSTEP(15, BO, BE, {})
#undef HSTEP
#undef LOADB
#undef OSTG

  // epilogue (vectorized): lane holds h0..h0+3 for token r16-indexed columns
  float part[4] = {0.f, 0.f, 0.f, 0.f};
#pragma unroll
  for (int hj = 0; hj < 8; ++hj) {
    int h0 = n0w + hj * 16 + lg * 4;
    f32x4 obv = *(const f32x4*)(ob + h0);
#pragma unroll
    for (int ti = 0; ti < 4; ++ti) {
      int t = m0 + ti * 16 + r16;
      u16x4 xv4 = *(const u16x4*)(xb + (size_t)t * DIM + h0);
#pragma unroll
      for (int rr = 0; rr < 4; ++rr) {
        float yv = bf2f(xv4[rr]) + acc[hj][ti][rr] + obv[rr];
        acc[hj][ti][rr] = yv;
        part[ti] += yv * yv;
      }
    }
  }
#pragma unroll
  for (int ti = 0; ti < 4; ++ti) {
    part[ti] += __shfl_xor(part[ti], 16);
    part[ti] += __shfl_xor(part[ti], 32);
  }
  if (lane < 16) {
#pragma unroll
    for (int ti = 0; ti < 4; ++ti) rowsum[ti * 16 + r16][w] = part[ti];
  }
  __syncthreads();
  float inv[4];
#pragma unroll
  for (int ti = 0; ti < 4; ++ti) {
    int tr = ti * 16 + r16;
    float s = rowsum[tr][0] + rowsum[tr][1] + rowsum[tr][2] + rowsum[tr][3];
    inv[ti] = 1.0f / sqrtf(s * (1.0f / 512.0f) + 1e-6f);
  }
#pragma unroll
  for (int hj = 0; hj < 8; ++hj) {
    int h0 = n0w + hj * 16 + lg * 4;
    f32x4 nwv = *(const f32x4*)(nw + h0);
#pragma unroll
    for (int ti = 0; ti < 4; ++ti) {
      int t = m0 + ti * 16 + r16;
      f32x4 o;
#pragma unroll
      for (int rr = 0; rr < 4; ++rr) o[rr] = acc[hj][ti][rr] * inv[ti] * nwv[rr];
      *(f32x4*)(out + (size_t)t * DIM + h0) = o;
    }
  }
}

extern "C" void kernel_launch(void* const* d_in, const int* in_sizes, int n_in,
                              void* d_out, int out_size, void* d_ws, size_t ws_size,
                              hipStream_t stream) {
  const float* x  = (const float*)d_in[0];
  const float* rw = (const float*)d_in[1];
  const float* rb = (const float*)d_in[2];
  const float* ew = (const float*)d_in[3];
  const float* eb = (const float*)d_in[4];
  const float* ow = (const float*)d_in[5];
  const float* ob = (const float*)d_in[6];
  const float* nw = (const float*)d_in[7];
  float* out = (float*)d_out;

  char* ws = (char*)d_ws;
  u16*   xb    = (u16*)(ws);                        // 64 MiB  x as bf16
  u16*   combb = (u16*)(ws + 67108864);             // 64 MiB  combined expert out (bf16)
  int*   pp    = (int*)(ws + 67108864);             // aliases combb (dead before it's written)
  float2* wab  = (float2*)(ws + 67108864 + 262144);
  u16*   ewt   = (u16*)(ws + 134217728);            // 2 MiB   expert_w^T bf16
  u16*   owt3  = (u16*)(ws + 136314880);            // 0.5 MiB out_w packed frags bf16
  int*   list  = (int*)(ws + 136839168);            // 336 KiB [6][REG] token ids
  float2* wpair = (float2*)(ws + 136839168 + 344064); // 672 KiB [6][REG] weights
  int*   cnt   = (int*)(ws + 136839168 + 344064 + 688128); // 24 B group counts

  wconv<<<dim3(256, 4), 256, 0, stream>>>(ew, ewt, cnt);
  owpack<<<128, 256, 0, stream>>>(ow, owt3);
  router_kernel<<<NTOK / 4, 256, 0, stream>>>(x, rw, rb, xb, pp, wab);
  assignscatter<<<NTOK / 256, 256, 0, stream>>>(pp, wab, cnt, list, wpair);
  expert_gemm<<<dim3(6 * REG / 128 * 4), 256, 0, stream>>>(xb, ewt, eb, cnt, list, wpair, combb);
  outnorm<<<dim3(NTOK / 64), 256, 0, stream>>>(combb, owt3, ob, xb, nw, out);
}

// Round 13
// 321.693 us; speedup vs baseline: 1.0248x; 1.0248x over previous
//
#include <hip/hip_runtime.h>
#include <hip/hip_bf16.h>
#include <stdint.h>

#define NTOK 65536
#define DIM 512
#define NEXP 4
#define REG 14336  // per-pair-group slot region (expected ~10923; 112 blocks of 128)

using u16 = unsigned short;
using u32 = unsigned int;
typedef __attribute__((ext_vector_type(4))) float f32x4;
typedef __attribute__((ext_vector_type(8))) short bf16x8;
typedef __attribute__((ext_vector_type(8))) u16 u16x8;
typedef __attribute__((ext_vector_type(4))) u16 u16x4;

__device__ __forceinline__ u16 f2bf(float f) {
  u32 u = __builtin_bit_cast(u32, f);
  u32 r = (u + 0x7FFFu + ((u >> 16) & 1u)) >> 16;
  return (u16)r;
}
__device__ __forceinline__ float bf2f(u16 v) {
  return __builtin_bit_cast(float, (u32)v << 16);
}

#define GLOAD_LDS16(gp, lp)                                                    \
  __builtin_amdgcn_global_load_lds(                                            \
      (const __attribute__((address_space(1))) void*)(gp),                     \
      (__attribute__((address_space(3))) void*)(lp), 16, 0, 0)

#define FENCE asm volatile("" ::: "memory")
#define BARRIER { FENCE; __builtin_amdgcn_s_barrier(); FENCE; }
#define LGKM0 { asm volatile("s_waitcnt lgkmcnt(0)" ::: "memory"); __builtin_amdgcn_sched_barrier(0); }
#define VMCNT_(n) asm volatile("s_waitcnt vmcnt(" #n ")" ::: "memory")
#define VMCNT(n) VMCNT_(n)
#define SB __builtin_amdgcn_sched_barrier(0)

// 128B-row LDS (outnorm): logical (row, 16B-chunk 0..7) -> phys chunk = c ^ (row&7)
__device__ __forceinline__ const bf16x8* lds_frag(const u16* base, int row, int chunk) {
  return (const bf16x8*)((const char*)base + row * 128 + (((chunk) ^ (row & 7)) << 4));
}
// 64B-row LDS (expert A, BK=32): logical chunk c (0..3) at phys (c + rot(row))&3,
// rot = ((row&15)>>1)&3. rchByte = precomputed phys byte offset for this lane.
__device__ __forceinline__ const bf16x8* frag32(const u16* base, int row, int rchByte) {
  return (const bf16x8*)((const char*)base + row * 64 + rchByte);
}

// ---------------- K0a: pack expert_w into MFMA-fragment order + cnt zero ----------
// frag f = (e*16 + T)*32 + hs ; lane l, q: ewtp[f*512 + l*8 + q]
//   = bf16(ew[e][d][h]),  d = T*32 + (l>>4)*8 + q,  h = hs*16 + (l&15)
__global__ void ewpack(const float* __restrict__ ew, u16* __restrict__ ewtp,
                       int* __restrict__ cnt) {
  if (blockIdx.x == 0 && threadIdx.x < 6) cnt[threadIdx.x] = 0;
  int lane = threadIdx.x & 63, wv = threadIdx.x >> 6;
  int f = blockIdx.x * 4 + wv;  // 0..2047
  int hs = f & 31, T = (f >> 5) & 15, e = f >> 9;
  int r16 = lane & 15, lg = lane >> 4;
  int h = hs * 16 + r16;
  int d0 = T * 32 + lg * 8;
  u16x8 o;
#pragma unroll
  for (int q = 0; q < 8; ++q)
    o[q] = f2bf(ew[((size_t)e * DIM + d0 + q) * DIM + h]);
  *(u16x8*)(ewtp + (size_t)f * 512 + lane * 8) = o;
}

// ---------------- K0b: pack out_w into MFMA-fragment order ----------------
__global__ void owpack(const float* __restrict__ ow, u16* __restrict__ owt3) {
  int lane = threadIdx.x & 63, wv = threadIdx.x >> 6;
  int frag = blockIdx.x * 4 + wv;  // 0..511
  int j = frag & 7, kc = (frag >> 3) & 1, t = (frag >> 4) & 7, strip = frag >> 7;
  int r16 = lane & 15, lg = lane >> 4;
  int h = strip * 128 + j * 16 + r16;
  int d0 = t * 64 + kc * 32 + lg * 8;
  u16x8 o;
#pragma unroll
  for (int q = 0; q < 8; ++q) o[q] = f2bf(ow[(size_t)(d0 + q) * DIM + h]);
  *(u16x8*)(owt3 + (size_t)frag * 512 + lane * 8) = o;
}

// ---------------- K1: router (fp32) + x -> bf16 ----------------
__global__ void router_kernel(const float* __restrict__ x, const float* __restrict__ rw,
                              const float* __restrict__ rb, u16* __restrict__ xb,
                              int* __restrict__ pp, float2* __restrict__ wab) {
  int lane = threadIdx.x & 63, wave = threadIdx.x >> 6;
  size_t t = (size_t)blockIdx.x * 4 + wave;
  const float* xr = x + t * DIM + lane * 8;
  f32x4 v0 = *(const f32x4*)xr;
  f32x4 v1 = *(const f32x4*)(xr + 4);
  float l0 = 0.f, l1 = 0.f, l2 = 0.f, l3 = 0.f;
  const float* rwp = rw + (size_t)lane * 32;
#pragma unroll
  for (int j = 0; j < 8; ++j) {
    float xv = (j < 4) ? v0[j] : v1[j - 4];
    f32x4 r = *(const f32x4*)(rwp + j * 4);
    l0 += xv * r[0]; l1 += xv * r[1]; l2 += xv * r[2]; l3 += xv * r[3];
  }
#pragma unroll
  for (int off = 32; off; off >>= 1) {
    l0 += __shfl_xor(l0, off); l1 += __shfl_xor(l1, off);
    l2 += __shfl_xor(l2, off); l3 += __shfl_xor(l3, off);
  }
  float lv[4] = {l0 + rb[0], l1 + rb[1], l2 + rb[2], l3 + rb[3]};
  int i0 = 0; float b0 = lv[0];
#pragma unroll
  for (int e = 1; e < 4; ++e) if (lv[e] > b0) { b0 = lv[e]; i0 = e; }
  int i1 = (i0 == 0) ? 1 : 0; float b1 = lv[i1];
#pragma unroll
  for (int e = 0; e < 4; ++e) if (e != i0 && lv[e] > b1) { b1 = lv[e]; i1 = e; }
  float ex = __expf(b1 - b0);
  float w0 = 1.0f / (1.0f + ex);
  float w1 = ex * w0;
  if (lane == 0) {
    int a = (i0 < i1) ? i0 : i1;
    int b = (i0 < i1) ? i1 : i0;
    const int ptab[16] = {-1, 0, 1, 2, -1, -1, 3, 4, -1, -1, -1, 5, -1, -1, -1, -1};
    pp[t] = ptab[a * 4 + b];
    float wa = (a == i0) ? w0 : w1;
    float wb = (a == i0) ? w1 : w0;
    wab[t] = make_float2(wa, wb);
  }
  u16x8 o;
#pragma unroll
  for (int j = 0; j < 4; ++j) { o[j] = f2bf(v0[j]); o[4 + j] = f2bf(v1[j]); }
  *(u16x8*)(xb + t * DIM + lane * 8) = o;
}

// ---------------- K2: wave-aggregated group assignment + scatter ----------------
__global__ void assignscatter(const int* __restrict__ pp, const float2* __restrict__ wab,
                              int* __restrict__ cnt, int* __restrict__ list,
                              float2* __restrict__ wpair) {
  int t = blockIdx.x * 256 + threadIdx.x;
  int lane = threadIdx.x & 63;
  int p = pp[t];
  float2 w = wab[t];
  int pos = 0;
#pragma unroll
  for (int q = 0; q < 6; ++q) {
    unsigned long long m = __ballot(p == q);
    if (p == q) {
      int rank = __popcll(m & ((1ull << lane) - 1ull));
      int leader = __ffsll((long long)m) - 1;
      int base = 0;
      if (lane == leader) base = atomicAdd(&cnt[q], (int)__popcll(m));
      base = __shfl(base, leader);
      pos = base + rank;
    }
  }
  int slot = p * REG + pos;
  if (pos < REG) {
    list[slot] = t;
    wpair[slot] = w;
  }
}

// ---------------- K3: sparse expert GEMM v8 — B direct from L2, motion-robust ----
// LDS holds ONLY gathered A (3 x 8 KB). Step T (pinned with sched_barrier):
// LOADB(T+1) -> SB -> STAGE A(T+2) -> SB -> 4 swizzled ds_reads -> 32 MFMA
// -> VMCNT(2) [keeps only A(T+2): A(T+1) provably LDS-resident] -> BARRIER.
__global__ __launch_bounds__(256, 2) void expert_gemm(
    const u16* __restrict__ xb, const u16* __restrict__ ewtp,
    const float* __restrict__ ebias, const int* __restrict__ cnt,
    const int* __restrict__ list, const float2* __restrict__ wpair,
    u16* __restrict__ comb) {
  __shared__ u16 Asl[3][128 * 32];  // 24 KB
  int tid = threadIdx.x, lane = tid & 63, wave = tid >> 6;
  int wy = wave >> 1, wx = wave & 1;
  int b = blockIdx.x;
  int chunk = b >> 5, within = b & 31;
  int panel = chunk * 8 + (within & 7);
  int nblk = within >> 3;
  int p = panel / (REG / 128);
  int m0 = panel * 128;
  int cntp = cnt[p];
  if (m0 - p * REG >= cntp) return;
  int n0 = nblk * 128;
  const int ea2[6] = {0, 0, 0, 1, 1, 2};
  const int eb2[6] = {1, 2, 3, 2, 3, 3};
  int eA = ea2[p], eB = eb2[p];

  int r4 = lane >> 2, c4 = lane & 3;
  int rot = (r4 >> 1) & 3;
  int kch = ((c4 - rot) & 3) * 8;
  int r16 = lane & 15, lg = lane >> 4;
  int rchB = (((lg + ((r16 >> 1) & 3)) & 3)) * 16;

  int sid2[2];
#pragma unroll
  for (int j = 0; j < 2; ++j) {
    int slot = m0 + wave * 32 + j * 16 + r4;
    int idv = list[slot];
    sid2[j] = ((slot - p * REG) < cntp) ? idv : 0;
  }
  const u16* a0b = xb + (size_t)sid2[0] * DIM + kch;
  const u16* a1b = xb + (size_t)sid2[1] * DIM + kch;
  // packed-fragment B bases: frag (e, T, hs) at (e*512 + T*32 + hs)*512 u16
  const u16* bpA = ewtp + (size_t)eA * 262144 + (size_t)(n0 / 16 + wx * 4) * 512 + lane * 8;
  const u16* bpB = ewtp + (size_t)eB * 262144 + (size_t)(n0 / 16 + wx * 4) * 512 + lane * 8;

  f32x4 accA[4][4], accB[4][4];
#pragma unroll
  for (int i = 0; i < 4; ++i)
#pragma unroll
    for (int j = 0; j < 4; ++j) { accA[i][j] = (f32x4)(0.f); accB[i][j] = (f32x4)(0.f); }

#define STAGE(BI, KS)                                                          \
  do {                                                                         \
    GLOAD_LDS16(a0b + (KS) * 32, Asl[BI] + (wave * 32) * 32);                  \
    GLOAD_LDS16(a1b + (KS) * 32, Asl[BI] + (wave * 32 + 16) * 32);             \
  } while (0)
#define LOADBX(BV, S)                                                          \
  do {                                                                         \
    _Pragma("unroll") for (int i = 0; i < 4; ++i) {                            \
      BV[i]     = *(const bf16x8*)(bpA + (S) * 16384 + i * 512);               \
      BV[4 + i] = *(const bf16x8*)(bpB + (S) * 16384 + i * 512);               \
    }                                                                          \
  } while (0)

  bf16x8 BE[8], BO[8];
  STAGE(0, 0); SB;
  STAGE(1, 1); SB;
  LOADBX(BE, 0); SB;
  VMCNT(10);   // pinned queue {A0:2, A1:2, B0:8} -> drains A0 (resident)
  BARRIER;

  // one fully-static K-step; T literal 0..15. BC = this step's B regs.
#define KST(T, BC, BN, WC)                                                     \
  {                                                                            \
    if ((T) + 1 < 16) { LOADBX(BN, (T) + 1); }                                 \
    SB;                                                                        \
    if ((T) + 2 < 16) { STAGE(((T) + 2) % 3, (T) + 2); }                       \
    SB;                                                                        \
    bf16x8 a[4];                                                               \
    _Pragma("unroll") for (int i = 0; i < 4; ++i)                              \
      a[i] = *frag32(Asl[(T) % 3], wy * 64 + i * 16 + r16, rchB);              \
    __builtin_amdgcn_s_setprio(1);                                             \
    _Pragma("unroll") for (int i = 0; i < 4; ++i)                              \
      _Pragma("unroll") for (int j = 0; j < 4; ++j)                            \
        accA[i][j] = __builtin_amdgcn_mfma_f32_16x16x32_bf16(a[i], BC[j], accA[i][j], 0, 0, 0); \
    _Pragma("unroll") for (int i = 0; i < 4; ++i)                              \
      _Pragma("unroll") for (int j = 0; j < 4; ++j)                            \
        accB[i][j] = __builtin_amdgcn_mfma_f32_16x16x32_bf16(a[i], BC[4 + j], accB[i][j], 0, 0, 0); \
    __builtin_amdgcn_s_setprio(0);                                             \
    WC;                                                                        \
  }

  KST(0,  BE, BO, { VMCNT(2); BARRIER; })
  KST(1,  BO, BE, { VMCNT(2); BARRIER; })
  KST(2,  BE, BO, { VMCNT(2); BARRIER; })
  KST(3,  BO, BE, { VMCNT(2); BARRIER; })
  KST(4,  BE, BO, { VMCNT(2); BARRIER; })
  KST(5,  BO, BE, { VMCNT(2); BARRIER; })
  KST(6,  BE, BO, { VMCNT(2); BARRIER; })
  KST(7,  BO, BE, { VMCNT(2); BARRIER; })
  KST(8,  BE, BO, { VMCNT(2); BARRIER; })
  KST(9,  BO, BE, { VMCNT(2); BARRIER; })
  KST(10, BE, BO, { VMCNT(2); BARRIER; })
  KST(11, BO, BE, { VMCNT(2); BARRIER; })
  KST(12, BE, BO, { VMCNT(2); BARRIER; })
  KST(13, BO, BE, { VMCNT(2); BARRIER; })
  KST(14, BE, BO, { VMCNT(2); BARRIER; })  // drains A(15); 2 of B(15) in flight
  KST(15, BO, BE, {})
#undef KST
#undef LOADBX
#undef STAGE

  float bA4[4], bB4[4];
#pragma unroll
  for (int j = 0; j < 4; ++j) {
    int h = n0 + wx * 64 + j * 16 + r16;
    bA4[j] = ebias[eA * DIM + h];
    bB4[j] = ebias[eB * DIM + h];
  }
#pragma unroll
  for (int i = 0; i < 4; ++i) {
    int rb = wy * 64 + i * 16 + lg * 4;
#pragma unroll
    for (int rr = 0; rr < 4; ++rr) {
      int slot = m0 + rb + rr;
      bool val = (slot - p * REG) < cntp;
      int id = list[slot];
      float2 wv = wpair[slot];
#pragma unroll
      for (int j = 0; j < 4; ++j) {
        float zA = accA[i][j][rr] + bA4[j];
        float zB = accB[i][j][rr] + bB4[j];
        float sA = zA / (1.0f + __expf(-zA));
        float sB = zB / (1.0f + __expf(-zB));
        float v = wv.x * sA + wv.y * sB;
        if (val) {
          int h = n0 + wx * 64 + j * 16 + r16;
          comb[(size_t)id * DIM + h] = f2bf(v);
        }
      }
    }
  }
}

// ---------------- K4: fused out-proj + bias + residual(bf16 xb) + RMSNorm ----------
// Swapped-operand MFMA: C rows = 4 consecutive h, cols = token.
__global__ __launch_bounds__(256, 2) void outnorm(
    const u16* __restrict__ comb, const u16* __restrict__ owt3,
    const float* __restrict__ ob, const u16* __restrict__ xb,
    const float* __restrict__ nw, float* __restrict__ out) {
  __shared__ u16 As[3][64 * 64];   // 24 KB
  __shared__ float rowsum[64][4];
  int tid = threadIdx.x, lane = tid & 63, w = tid >> 6;  // 4 waves
  int m0 = blockIdx.x * 64;
  int r16 = lane & 15, lg = lane >> 4;
  int rl = lane >> 3;
  int scb = ((lane & 7) ^ rl) * 8;
  int n0w = w * 128;

  f32x4 acc[8][4];  // [h-frag][token-frag]
#pragma unroll
  for (int j = 0; j < 8; ++j)
#pragma unroll
    for (int i = 0; i < 4; ++i) acc[j][i] = (f32x4)(0.f);

#define OSTG(bi, ks)                                                           \
  _Pragma("unroll") for (int jj = 0; jj < 2; ++jj) {                           \
    GLOAD_LDS16(comb + (size_t)(m0 + w * 16 + jj * 8 + rl) * DIM + (ks) * 64 + scb, \
                As[bi] + (w * 16 + jj * 8) * 64);                              \
  }
#define LOADB(BV, HH)                                                          \
  {                                                                            \
    const u16* bp_ = owt3 +                                                    \
        ((size_t)(((w * 8 + ((HH) >> 1)) * 2 + ((HH) & 1)) * 8)) * 512 + lane * 8; \
    _Pragma("unroll") for (int jj = 0; jj < 8; ++jj)                           \
      BV[jj] = *(const bf16x8*)(bp_ + jj * 512);                               \
  }
#define HSTEP(H, BC, BN, WC)                                                   \
  {                                                                            \
    if (((H) & 1) == 0 && ((H) >> 1) + 2 < 8) OSTG((((H) >> 1) + 2) % 3, ((H) >> 1) + 2); \
    if ((H) + 1 < 16) LOADB(BN, (H) + 1);                                      \
    bf16x8 af[4];                                                              \
    _Pragma("unroll") for (int ii = 0; ii < 4; ++ii)                           \
      af[ii] = *lds_frag(As[((H) >> 1) % 3], ii * 16 + r16, ((H) & 1) * 4 + lg); \
    LGKM0;                                                                     \
    __builtin_amdgcn_s_setprio(1);                                             \
    _Pragma("unroll") for (int jj = 0; jj < 8; ++jj)                           \
      _Pragma("unroll") for (int ii = 0; ii < 4; ++ii)                         \
        acc[jj][ii] = __builtin_amdgcn_mfma_f32_16x16x32_bf16(BC[jj], af[ii], acc[jj][ii], 0, 0, 0); \
    __builtin_amdgcn_s_setprio(0);                                             \
    WC;                                                                        \
  }

  bf16x8 BE[8], BO[8];
  OSTG(0, 0); OSTG(1, 1);
  LOADB(BE, 0);
  VMCNT(10);   // drain A0 (A1 2 + BE0 8 stay in flight)
  BARRIER;

  HSTEP(0,  BE, BO, {})
  HSTEP(1,  BO, BE, { VMCNT(10); BARRIER; })
  HSTEP(2,  BE, BO, {})
  HSTEP(3,  BO, BE, { VMCNT(10); BARRIER; })
  HSTEP(4,  BE, BO, {})
  HSTEP(5,  BO, BE, { VMCNT(10); BARRIER; })
  HSTEP(6,  BE, BO, {})
  HSTEP(7,  BO, BE, { VMCNT(10); BARRIER; })
  HSTEP(8,  BE, BO, {})
  HSTEP(9,  BO, BE, { VMCNT(10); BARRIER; })
  HSTEP(10, BE, BO, {})
  HSTEP(11, BO, BE, { VMCNT(10); BARRIER; })
  HSTEP(12, BE, BO, {})
  HSTEP(13, BO, BE, { VMCNT(8); BARRIER; })
  HSTEP(14, BE, BO, {})
  HSTEP(15, BO, BE, {})
#undef HSTEP
#undef LOADB
#undef OSTG

  // epilogue (vectorized): lane holds h0..h0+3 for token r16-indexed columns
  float part[4] = {0.f, 0.f, 0.f, 0.f};
#pragma unroll
  for (int hj = 0; hj < 8; ++hj) {
    int h0 = n0w + hj * 16 + lg * 4;
    f32x4 obv = *(const f32x4*)(ob + h0);
#pragma unroll
    for (int ti = 0; ti < 4; ++ti) {
      int t = m0 + ti * 16 + r16;
      u16x4 xv4 = *(const u16x4*)(xb + (size_t)t * DIM + h0);
#pragma unroll
      for (int rr = 0; rr < 4; ++rr) {
        float yv = bf2f(xv4[rr]) + acc[hj][ti][rr] + obv[rr];
        acc[hj][ti][rr] = yv;
        part[ti] += yv * yv;
      }
    }
  }
#pragma unroll
  for (int ti = 0; ti < 4; ++ti) {
    part[ti] += __shfl_xor(part[ti], 16);
    part[ti] += __shfl_xor(part[ti], 32);
  }
  if (lane < 16) {
#pragma unroll
    for (int ti = 0; ti < 4; ++ti) rowsum[ti * 16 + r16][w] = part[ti];
  }
  __syncthreads();
  float inv[4];
#pragma unroll
  for (int ti = 0; ti < 4; ++ti) {
    int tr = ti * 16 + r16;
    float s = rowsum[tr][0] + rowsum[tr][1] + rowsum[tr][2] + rowsum[tr][3];
    inv[ti] = 1.0f / sqrtf(s * (1.0f / 512.0f) + 1e-6f);
  }
#pragma unroll
  for (int hj = 0; hj < 8; ++hj) {
    int h0 = n0w + hj * 16 + lg * 4;
    f32x4 nwv = *(const f32x4*)(nw + h0);
#pragma unroll
    for (int ti = 0; ti < 4; ++ti) {
      int t = m0 + ti * 16 + r16;
      f32x4 o;
#pragma unroll
      for (int rr = 0; rr < 4; ++rr) o[rr] = acc[hj][ti][rr] * inv[ti] * nwv[rr];
      *(f32x4*)(out + (size_t)t * DIM + h0) = o;
    }
  }
}

extern "C" void kernel_launch(void* const* d_in, const int* in_sizes, int n_in,
                              void* d_out, int out_size, void* d_ws, size_t ws_size,
                              hipStream_t stream) {
  const float* x  = (const float*)d_in[0];
  const float* rw = (const float*)d_in[1];
  const float* rb = (const float*)d_in[2];
  const float* ew = (const float*)d_in[3];
  const float* eb = (const float*)d_in[4];
  const float* ow = (const float*)d_in[5];
  const float* ob = (const float*)d_in[6];
  const float* nw = (const float*)d_in[7];
  float* out = (float*)d_out;

  char* ws = (char*)d_ws;
  u16*   xb    = (u16*)(ws);                        // 64 MiB  x as bf16
  u16*   combb = (u16*)(ws + 67108864);             // 64 MiB  combined expert out (bf16)
  int*   pp    = (int*)(ws + 67108864);             // aliases combb (dead before it's written)
  float2* wab  = (float2*)(ws + 67108864 + 262144);
  u16*   ewtp  = (u16*)(ws + 134217728);            // 2 MiB   expert_w packed frags bf16
  u16*   owt3  = (u16*)(ws + 136314880);            // 0.5 MiB out_w packed frags bf16
  int*   list  = (int*)(ws + 136839168);            // 336 KiB [6][REG] token ids
  float2* wpair = (float2*)(ws + 136839168 + 344064); // 672 KiB [6][REG] weights
  int*   cnt   = (int*)(ws + 136839168 + 344064 + 688128); // 24 B group counts

  ewpack<<<512, 256, 0, stream>>>(ew, ewtp, cnt);
  owpack<<<128, 256, 0, stream>>>(ow, owt3);
  router_kernel<<<NTOK / 4, 256, 0, stream>>>(x, rw, rb, xb, pp, wab);
  assignscatter<<<NTOK / 256, 256, 0, stream>>>(pp, wab, cnt, list, wpair);
  expert_gemm<<<dim3(6 * REG / 128 * 4), 256, 0, stream>>>(xb, ewtp, eb, cnt, list, wpair, combb);
  outnorm<<<dim3(NTOK / 64), 256, 0, stream>>>(combb, owt3, ob, xb, nw, out);
}

// Round 14
// 317.435 us; speedup vs baseline: 1.0385x; 1.0134x over previous
//
#include <hip/hip_runtime.h>
#include <hip/hip_bf16.h>
#include <stdint.h>

#define NTOK 65536
#define DIM 512
#define NEXP 4
#define REG 14336  // per-pair-group slot region (expected ~10923; 112 blocks of 128)

using u16 = unsigned short;
using u32 = unsigned int;
typedef __attribute__((ext_vector_type(4))) float f32x4;
typedef __attribute__((ext_vector_type(8))) short bf16x8;
typedef __attribute__((ext_vector_type(8))) u16 u16x8;
typedef __attribute__((ext_vector_type(4))) u16 u16x4;

__device__ __forceinline__ u16 f2bf(float f) {
  u32 u = __builtin_bit_cast(u32, f);
  u32 r = (u + 0x7FFFu + ((u >> 16) & 1u)) >> 16;
  return (u16)r;
}
__device__ __forceinline__ float bf2f(u16 v) {
  return __builtin_bit_cast(float, (u32)v << 16);
}

#define GLOAD_LDS16(gp, lp)                                                    \
  __builtin_amdgcn_global_load_lds(                                            \
      (const __attribute__((address_space(1))) void*)(gp),                     \
      (__attribute__((address_space(3))) void*)(lp), 16, 0, 0)

#define FENCE asm volatile("" ::: "memory")
#define BARRIER { FENCE; __builtin_amdgcn_s_barrier(); FENCE; }
#define LGKM0 { asm volatile("s_waitcnt lgkmcnt(0)" ::: "memory"); __builtin_amdgcn_sched_barrier(0); }
#define VMCNT_(n) asm volatile("s_waitcnt vmcnt(" #n ")" ::: "memory")
#define VMCNT(n) VMCNT_(n)
#define SB __builtin_amdgcn_sched_barrier(0)

// 128B-row LDS: logical (row, 16B-chunk 0..7) -> phys chunk = c ^ (row&7)
__device__ __forceinline__ const bf16x8* lds_frag(const u16* base, int row, int chunk) {
  return (const bf16x8*)((const char*)base + row * 128 + (((chunk) ^ (row & 7)) << 4));
}

// ---------------- K0: pack expert_w + out_w into MFMA-fragment order + cnt zero ----
// expert frag f = (e*16 + T32)*32 + hs : ewtp[f*512 + l*8 + q]
//   = bf16(ew[e][d][h]), d = T32*32 + (l>>4)*8 + q, h = hs*16 + (l&15)
// out frag = ((strip*8 + t)*2 + kc)*8 + j : owt3[frag*512 + l*8 + q]
//   = bf16(ow[d][h]), d = t*64 + kc*32 + (l>>4)*8 + q, h = strip*128 + j*16 + (l&15)
__global__ void packw(const float* __restrict__ ew, const float* __restrict__ ow,
                      u16* __restrict__ ewtp, u16* __restrict__ owt3,
                      int* __restrict__ cnt) {
  if (blockIdx.x == 0 && threadIdx.x < 6) cnt[threadIdx.x] = 0;
  int lane = threadIdx.x & 63, wv = threadIdx.x >> 6;
  int gf = blockIdx.x * 4 + wv;  // 0..2559
  int r16 = lane & 15, lg = lane >> 4;
  u16x8 o;
  if (gf < 2048) {
    int hs = gf & 31, T = (gf >> 5) & 15, e = gf >> 9;
    int h = hs * 16 + r16;
    int d0 = T * 32 + lg * 8;
#pragma unroll
    for (int q = 0; q < 8; ++q)
      o[q] = f2bf(ew[((size_t)e * DIM + d0 + q) * DIM + h]);
    *(u16x8*)(ewtp + (size_t)gf * 512 + lane * 8) = o;
  } else {
    int frag = gf - 2048;
    int j = frag & 7, kc = (frag >> 3) & 1, t = (frag >> 4) & 7, strip = frag >> 7;
    int h = strip * 128 + j * 16 + r16;
    int d0 = t * 64 + kc * 32 + lg * 8;
#pragma unroll
    for (int q = 0; q < 8; ++q) o[q] = f2bf(ow[(size_t)(d0 + q) * DIM + h]);
    *(u16x8*)(owt3 + (size_t)frag * 512 + lane * 8) = o;
  }
}

// ---------------- K1: router (fp32) + x -> bf16 ----------------
__global__ void router_kernel(const float* __restrict__ x, const float* __restrict__ rw,
                              const float* __restrict__ rb, u16* __restrict__ xb,
                              int* __restrict__ pp, float2* __restrict__ wab) {
  int lane = threadIdx.x & 63, wave = threadIdx.x >> 6;
  size_t t = (size_t)blockIdx.x * 4 + wave;
  const float* xr = x + t * DIM + lane * 8;
  f32x4 v0 = *(const f32x4*)xr;
  f32x4 v1 = *(const f32x4*)(xr + 4);
  float l0 = 0.f, l1 = 0.f, l2 = 0.f, l3 = 0.f;
  const float* rwp = rw + (size_t)lane * 32;
#pragma unroll
  for (int j = 0; j < 8; ++j) {
    float xv = (j < 4) ? v0[j] : v1[j - 4];
    f32x4 r = *(const f32x4*)(rwp + j * 4);
    l0 += xv * r[0]; l1 += xv * r[1]; l2 += xv * r[2]; l3 += xv * r[3];
  }
#pragma unroll
  for (int off = 32; off; off >>= 1) {
    l0 += __shfl_xor(l0, off); l1 += __shfl_xor(l1, off);
    l2 += __shfl_xor(l2, off); l3 += __shfl_xor(l3, off);
  }
  float lv[4] = {l0 + rb[0], l1 + rb[1], l2 + rb[2], l3 + rb[3]};
  int i0 = 0; float b0 = lv[0];
#pragma unroll
  for (int e = 1; e < 4; ++e) if (lv[e] > b0) { b0 = lv[e]; i0 = e; }
  int i1 = (i0 == 0) ? 1 : 0; float b1 = lv[i1];
#pragma unroll
  for (int e = 0; e < 4; ++e) if (e != i0 && lv[e] > b1) { b1 = lv[e]; i1 = e; }
  float ex = __expf(b1 - b0);
  float w0 = 1.0f / (1.0f + ex);
  float w1 = ex * w0;
  if (lane == 0) {
    int a = (i0 < i1) ? i0 : i1;
    int b = (i0 < i1) ? i1 : i0;
    const int ptab[16] = {-1, 0, 1, 2, -1, -1, 3, 4, -1, -1, -1, 5, -1, -1, -1, -1};
    pp[t] = ptab[a * 4 + b];
    float wa = (a == i0) ? w0 : w1;
    float wb = (a == i0) ? w1 : w0;
    wab[t] = make_float2(wa, wb);
  }
  u16x8 o;
#pragma unroll
  for (int j = 0; j < 4; ++j) { o[j] = f2bf(v0[j]); o[4 + j] = f2bf(v1[j]); }
  *(u16x8*)(xb + t * DIM + lane * 8) = o;
}

// ---------------- K2: wave-aggregated group assignment + scatter ----------------
__global__ void assignscatter(const int* __restrict__ pp, const float2* __restrict__ wab,
                              int* __restrict__ cnt, int* __restrict__ list,
                              float2* __restrict__ wpair) {
  int t = blockIdx.x * 256 + threadIdx.x;
  int lane = threadIdx.x & 63;
  int p = pp[t];
  float2 w = wab[t];
  int pos = 0;
#pragma unroll
  for (int q = 0; q < 6; ++q) {
    unsigned long long m = __ballot(p == q);
    if (p == q) {
      int rank = __popcll(m & ((1ull << lane) - 1ull));
      int leader = __ffsll((long long)m) - 1;
      int base = 0;
      if (lane == leader) base = atomicAdd(&cnt[q], (int)__popcll(m));
      base = __shfl(base, leader);
      pos = base + rank;
    }
  }
  int slot = p * REG + pos;
  if (pos < REG) {
    list[slot] = t;
    wpair[slot] = w;
  }
}

// ---------------- K3: sparse expert GEMM v9 — BK=64, 8 steps, 8 barriers ----------
// LDS: 3 x 16 KB A buffers (128 rows x 128 B, XOR-swizzled). Per step T:
// [Bk0+Bk1 16 L2 frag loads] SB [stage A(T+2): 4 gloads] SB
// [ds a(kc0) x4 -> 16 MFMA] [ds a(kc1) x4 -> 16 MFMA] VMCNT(4) BARRIER.
// End-of-step leaves ONLY A(T+2) in flight (~2 steps of gather-latency cover).
__global__ __launch_bounds__(256, 2) void expert_gemm(
    const u16* __restrict__ xb, const u16* __restrict__ ewtp,
    const float* __restrict__ ebias, const int* __restrict__ cnt,
    const int* __restrict__ list, const float2* __restrict__ wpair,
    u16* __restrict__ comb) {
  __shared__ u16 Asl[3][128 * 64];  // 48 KB
  int tid = threadIdx.x, lane = tid & 63, wave = tid >> 6;
  int wy = wave >> 1, wx = wave & 1;
  int b = blockIdx.x;
  int chunk = b >> 5, within = b & 31;
  int panel = chunk * 8 + (within & 7);
  int nblk = within >> 3;
  int p = panel / (REG / 128);
  int m0 = panel * 128;
  int cntp = cnt[p];
  if (m0 - p * REG >= cntp) return;
  int n0 = nblk * 128;
  const int ea2[6] = {0, 0, 0, 1, 1, 2};
  const int eb2[6] = {1, 2, 3, 2, 3, 3};
  int eA = ea2[p], eB = eb2[p];

  int r16 = lane & 15, lg = lane >> 4;
  int rl = lane >> 3;                  // staging row within 8-row group
  int scb = ((lane & 7) ^ rl) * 8;     // pre-swizzled source elem offset
  // ds-read byte offsets: phys chunk bits = [kc^s2, lg1^s1, lg0^s0], s=r16&7
  int s = r16 & 7;
  int ab0 = (wy * 64 + r16) * 128 + ((s >> 2) << 6) + ((lg ^ (s & 3)) << 4);
  int ab1 = ab0 ^ 64;  // kc=1 (row*128 has no bit6 component: stride 128)

  int sid[4];
#pragma unroll
  for (int j = 0; j < 4; ++j) {
    int slot = m0 + wave * 32 + j * 8 + rl;
    int idv = list[slot];
    sid[j] = ((slot - p * REG) < cntp) ? idv : 0;
  }
  const u16* a0b = xb + (size_t)sid[0] * DIM + scb;
  const u16* a1b = xb + (size_t)sid[1] * DIM + scb;
  const u16* a2b = xb + (size_t)sid[2] * DIM + scb;
  const u16* a3b = xb + (size_t)sid[3] * DIM + scb;
  // packed-fragment B bases: frag (e, T32, hs) at (e*512 + T32*32 + hs)*512 u16
  const u16* bpA = ewtp + (size_t)eA * 262144 + (size_t)(n0 / 16 + wx * 4) * 512 + lane * 8;
  const u16* bpB = ewtp + (size_t)eB * 262144 + (size_t)(n0 / 16 + wx * 4) * 512 + lane * 8;

  f32x4 accA[4][4], accB[4][4];
#pragma unroll
  for (int i = 0; i < 4; ++i)
#pragma unroll
    for (int j = 0; j < 4; ++j) { accA[i][j] = (f32x4)(0.f); accB[i][j] = (f32x4)(0.f); }

#define STAGE(BI, KS)                                                          \
  do {                                                                         \
    GLOAD_LDS16(a0b + (KS) * 64, Asl[BI] + (wave * 32) * 64);                  \
    GLOAD_LDS16(a1b + (KS) * 64, Asl[BI] + (wave * 32 + 8) * 64);              \
    GLOAD_LDS16(a2b + (KS) * 64, Asl[BI] + (wave * 32 + 16) * 64);             \
    GLOAD_LDS16(a3b + (KS) * 64, Asl[BI] + (wave * 32 + 24) * 64);             \
  } while (0)
#define LOADB(BV, T32)                                                         \
  do {                                                                         \
    _Pragma("unroll") for (int i = 0; i < 4; ++i) {                            \
      BV[i]     = *(const bf16x8*)(bpA + (T32) * 16384 + i * 512);             \
      BV[4 + i] = *(const bf16x8*)(bpB + (T32) * 16384 + i * 512);             \
    }                                                                          \
  } while (0)

  STAGE(0, 0); SB;
  STAGE(1, 1); SB;
  VMCNT(4);   // A0 resident; A1 in flight (covered by step 0)
  BARRIER;

  bf16x8 Bk0[8], Bk1[8];
  // one fully-static K-step; T literal 0..7
#define KST(T, WC)                                                             \
  {                                                                            \
    LOADB(Bk0, 2 * (T));                                                       \
    LOADB(Bk1, 2 * (T) + 1);                                                   \
    SB;                                                                        \
    if ((T) + 2 < 8) { STAGE(((T) + 2) % 3, (T) + 2); }                        \
    SB;                                                                        \
    const char* Ab_ = (const char*)Asl[(T) % 3];                               \
    bf16x8 a[4];                                                               \
    _Pragma("unroll") for (int i = 0; i < 4; ++i)                              \
      a[i] = *(const bf16x8*)(Ab_ + ab0 + i * 2048);                           \
    __builtin_amdgcn_s_setprio(1);                                             \
    _Pragma("unroll") for (int i = 0; i < 4; ++i)                              \
      _Pragma("unroll") for (int j = 0; j < 4; ++j)                            \
        accA[i][j] = __builtin_amdgcn_mfma_f32_16x16x32_bf16(a[i], Bk0[j], accA[i][j], 0, 0, 0); \
    _Pragma("unroll") for (int i = 0; i < 4; ++i)                              \
      _Pragma("unroll") for (int j = 0; j < 4; ++j)                            \
        accB[i][j] = __builtin_amdgcn_mfma_f32_16x16x32_bf16(a[i], Bk0[4 + j], accB[i][j], 0, 0, 0); \
    __builtin_amdgcn_s_setprio(0);                                             \
    _Pragma("unroll") for (int i = 0; i < 4; ++i)                              \
      a[i] = *(const bf16x8*)(Ab_ + ab1 + i * 2048);                           \
    __builtin_amdgcn_s_setprio(1);                                             \
    _Pragma("unroll") for (int i = 0; i < 4; ++i)                              \
      _Pragma("unroll") for (int j = 0; j < 4; ++j)                            \
        accA[i][j] = __builtin_amdgcn_mfma_f32_16x16x32_bf16(a[i], Bk1[j], accA[i][j], 0, 0, 0); \
    _Pragma("unroll") for (int i = 0; i < 4; ++i)                              \
      _Pragma("unroll") for (int j = 0; j < 4; ++j)                            \
        accB[i][j] = __builtin_amdgcn_mfma_f32_16x16x32_bf16(a[i], Bk1[4 + j], accB[i][j], 0, 0, 0); \
    __builtin_amdgcn_s_setprio(0);                                             \
    WC;                                                                        \
  }

  KST(0, { VMCNT(4); BARRIER; })
  KST(1, { VMCNT(4); BARRIER; })
  KST(2, { VMCNT(4); BARRIER; })
  KST(3, { VMCNT(4); BARRIER; })
  KST(4, { VMCNT(4); BARRIER; })
  KST(5, { VMCNT(4); BARRIER; })
  KST(6, { VMCNT(0); BARRIER; })  // no stage issued this step; drain A(7)
  KST(7, {})
#undef KST
#undef LOADB
#undef STAGE

  float bA4[4], bB4[4];
#pragma unroll
  for (int j = 0; j < 4; ++j) {
    int h = n0 + wx * 64 + j * 16 + r16;
    bA4[j] = ebias[eA * DIM + h];
    bB4[j] = ebias[eB * DIM + h];
  }
#pragma unroll
  for (int i = 0; i < 4; ++i) {
    int rb = wy * 64 + i * 16 + lg * 4;
#pragma unroll
    for (int rr = 0; rr < 4; ++rr) {
      int slot = m0 + rb + rr;
      bool val = (slot - p * REG) < cntp;
      int id = list[slot];
      float2 wv = wpair[slot];
#pragma unroll
      for (int j = 0; j < 4; ++j) {
        float zA = accA[i][j][rr] + bA4[j];
        float zB = accB[i][j][rr] + bB4[j];
        float sA = zA / (1.0f + __expf(-zA));
        float sB = zB / (1.0f + __expf(-zB));
        float v = wv.x * sA + wv.y * sB;
        if (val) {
          int h = n0 + wx * 64 + j * 16 + r16;
          comb[(size_t)id * DIM + h] = f2bf(v);
        }
      }
    }
  }
}

// ---------------- K4: fused out-proj + bias + residual(bf16 xb) + RMSNorm ----------
// Swapped-operand MFMA: C rows = 4 consecutive h, cols = token.
__global__ __launch_bounds__(256, 2) void outnorm(
    const u16* __restrict__ comb, const u16* __restrict__ owt3,
    const float* __restrict__ ob, const u16* __restrict__ xb,
    const float* __restrict__ nw, float* __restrict__ out) {
  __shared__ u16 As[3][64 * 64];   // 24 KB
  __shared__ float rowsum[64][4];
  int tid = threadIdx.x, lane = tid & 63, w = tid >> 6;  // 4 waves
  int m0 = blockIdx.x * 64;
  int r16 = lane & 15, lg = lane >> 4;
  int rl = lane >> 3;
  int scb = ((lane & 7) ^ rl) * 8;
  int n0w = w * 128;

  f32x4 acc[8][4];  // [h-frag][token-frag]
#pragma unroll
  for (int j = 0; j < 8; ++j)
#pragma unroll
    for (int i = 0; i < 4; ++i) acc[j][i] = (f32x4)(0.f);

#define OSTG(bi, ks)                                                           \
  _Pragma("unroll") for (int jj = 0; jj < 2; ++jj) {                           \
    GLOAD_LDS16(comb + (size_t)(m0 + w * 16 + jj * 8 + rl) * DIM + (ks) * 64 + scb, \
                As[bi] + (w * 16 + jj * 8) * 64);                              \
  }
#define LOADB(BV, HH)                                                          \
  {                                                                            \
    const u16* bp_ = owt3 +                                                    \
        ((size_t)(((w * 8 + ((HH) >> 1)) * 2 + ((HH) & 1)) * 8)) * 512 + lane * 8; \
    _Pragma("unroll") for (int jj = 0; jj < 8; ++jj)                           \
      BV[jj] = *(const bf16x8*)(bp_ + jj * 512);                               \
  }
#define HSTEP(H, BC, BN, WC)                                                   \
  {                                                                            \
    if (((H) & 1) == 0 && ((H) >> 1) + 2 < 8) OSTG((((H) >> 1) + 2) % 3, ((H) >> 1) + 2); \
    if ((H) + 1 < 16) LOADB(BN, (H) + 1);                                      \
    bf16x8 af[4];                                                              \
    _Pragma("unroll") for (int ii = 0; ii < 4; ++ii)                           \
      af[ii] = *lds_frag(As[((H) >> 1) % 3], ii * 16 + r16, ((H) & 1) * 4 + lg); \
    LGKM0;                                                                     \
    __builtin_amdgcn_s_setprio(1);                                             \
    _Pragma("unroll") for (int jj = 0; jj < 8; ++jj)                           \
      _Pragma("unroll") for (int ii = 0; ii < 4; ++ii)                         \
        acc[jj][ii] = __builtin_amdgcn_mfma_f32_16x16x32_bf16(BC[jj], af[ii], acc[jj][ii], 0, 0, 0); \
    __builtin_amdgcn_s_setprio(0);                                             \
    WC;                                                                        \
  }

  bf16x8 BE[8], BO[8];
  OSTG(0, 0); OSTG(1, 1);
  LOADB(BE, 0);
  VMCNT(10);   // drain A0 (A1 2 + BE0 8 stay in flight)
  BARRIER;

  HSTEP(0,  BE, BO, {})
  HSTEP(1,  BO, BE, { VMCNT(10); BARRIER; })
  HSTEP(2,  BE, BO, {})
  HSTEP(3,  BO, BE, { VMCNT(10); BARRIER; })
  HSTEP(4,  BE, BO, {})
  HSTEP(5,  BO, BE, { VMCNT(10); BARRIER; })
  HSTEP(6,  BE, BO, {})
  HSTEP(7,  BO, BE, { VMCNT(10); BARRIER; })
  HSTEP(8,  BE, BO, {})
  HSTEP(9,  BO, BE, { VMCNT(10); BARRIER; })
  HSTEP(10, BE, BO, {})
  HSTEP(11, BO, BE, { VMCNT(10); BARRIER; })
  HSTEP(12, BE, BO, {})
  HSTEP(13, BO, BE, { VMCNT(8); BARRIER; })
  HSTEP(14, BE, BO, {})
  HSTEP(15, BO, BE, {})
#undef HSTEP
#undef LOADB
#undef OSTG

  // epilogue (vectorized): lane holds h0..h0+3 for token r16-indexed columns
  float part[4] = {0.f, 0.f, 0.f, 0.f};
#pragma unroll
  for (int hj = 0; hj < 8; ++hj) {
    int h0 = n0w + hj * 16 + lg * 4;
    f32x4 obv = *(const f32x4*)(ob + h0);
#pragma unroll
    for (int ti = 0; ti < 4; ++ti) {
      int t = m0 + ti * 16 + r16;
      u16x4 xv4 = *(const u16x4*)(xb + (size_t)t * DIM + h0);
#pragma unroll
      for (int rr = 0; rr < 4; ++rr) {
        float yv = bf2f(xv4[rr]) + acc[hj][ti][rr] + obv[rr];
        acc[hj][ti][rr] = yv;
        part[ti] += yv * yv;
      }
    }
  }
#pragma unroll
  for (int ti = 0; ti < 4; ++ti) {
    part[ti] += __shfl_xor(part[ti], 16);
    part[ti] += __shfl_xor(part[ti], 32);
  }
  if (lane < 16) {
#pragma unroll
    for (int ti = 0; ti < 4; ++ti) rowsum[ti * 16 + r16][w] = part[ti];
  }
  __syncthreads();
  float inv[4];
#pragma unroll
  for (int ti = 0; ti < 4; ++ti) {
    int tr = ti * 16 + r16;
    float s = rowsum[tr][0] + rowsum[tr][1] + rowsum[tr][2] + rowsum[tr][3];
    inv[ti] = 1.0f / sqrtf(s * (1.0f / 512.0f) + 1e-6f);
  }
#pragma unroll
  for (int hj = 0; hj < 8; ++hj) {
    int h0 = n0w + hj * 16 + lg * 4;
    f32x4 nwv = *(const f32x4*)(nw + h0);
#pragma unroll
    for (int ti = 0; ti < 4; ++ti) {
      int t = m0 + ti * 16 + r16;
      f32x4 o;
#pragma unroll
      for (int rr = 0; rr < 4; ++rr) o[rr] = acc[hj][ti][rr] * inv[ti] * nwv[rr];
      *(f32x4*)(out + (size_t)t * DIM + h0) = o;
    }
  }
}

extern "C" void kernel_launch(void* const* d_in, const int* in_sizes, int n_in,
                              void* d_out, int out_size, void* d_ws, size_t ws_size,
                              hipStream_t stream) {
  const float* x  = (const float*)d_in[0];
  const float* rw = (const float*)d_in[1];
  const float* rb = (const float*)d_in[2];
  const float* ew = (const float*)d_in[3];
  const float* eb = (const float*)d_in[4];
  const float* ow = (const float*)d_in[5];
  const float* ob = (const float*)d_in[6];
  const float* nw = (const float*)d_in[7];
  float* out = (float*)d_out;

  char* ws = (char*)d_ws;
  u16*   xb    = (u16*)(ws);                        // 64 MiB  x as bf16
  u16*   combb = (u16*)(ws + 67108864);             // 64 MiB  combined expert out (bf16)
  int*   pp    = (int*)(ws + 67108864);             // aliases combb (dead before it's written)
  float2* wab  = (float2*)(ws + 67108864 + 262144);
  u16*   ewtp  = (u16*)(ws + 134217728);            // 2 MiB   expert_w packed frags bf16
  u16*   owt3  = (u16*)(ws + 136314880);            // 0.5 MiB out_w packed frags bf16
  int*   list  = (int*)(ws + 136839168);            // 336 KiB [6][REG] token ids
  float2* wpair = (float2*)(ws + 136839168 + 344064); // 672 KiB [6][REG] weights
  int*   cnt   = (int*)(ws + 136839168 + 344064 + 688128); // 24 B group counts

  packw<<<640, 256, 0, stream>>>(ew, ow, ewtp, owt3, cnt);
  router_kernel<<<NTOK / 4, 256, 0, stream>>>(x, rw, rb, xb, pp, wab);
  assignscatter<<<NTOK / 256, 256, 0, stream>>>(pp, wab, cnt, list, wpair);
  expert_gemm<<<dim3(6 * REG / 128 * 4), 256, 0, stream>>>(xb, ewtp, eb, cnt, list, wpair, combb);
  outnorm<<<dim3(NTOK / 64), 256, 0, stream>>>(combb, owt3, ob, xb, nw, out);
}